// Round 1
// baseline (259.354 us; speedup 1.0000x reference)
//
#include <hip/hip_runtime.h>
#include <stdint.h>

#define N 4096
#define B 2
#define D 128
#define LOG2E 1.4426950408889634f

typedef float f32x4 __attribute__((ext_vector_type(4)));

__device__ __forceinline__ float lrelu(float t) { return t > 0.f ? t : 0.01f * t; }

// order-preserving float<->uint for atomicMax on signed floats
__device__ __forceinline__ unsigned f2ord(float f) {
    unsigned u = __float_as_uint(f);
    return (u & 0x80000000u) ? ~u : (u | 0x80000000u);
}
__device__ __forceinline__ float ord2f(unsigned o) {
    return __uint_as_float((o & 0x80000000u) ? (o ^ 0x80000000u) : ~o);
}

// K1: u_l[d] = sum_e Wa[e*D+d]*w_l[e]; u_r likewise. 1 block x 256 threads.
// Also zero-inits the per-batch rmax atomics (ws is poisoned, k1 runs first).
__global__ __launch_bounds__(256) void k1_uvec(
    const float* __restrict__ Wa,
    const float* __restrict__ w_l,
    const float* __restrict__ w_r,
    float* __restrict__ u,            // u[0..D)=u_l, u[D..2D)=u_r
    unsigned* __restrict__ gmax) {    // [B] ordered-uint max of r (exp2 domain)
    __shared__ float2 pl[4][64];
    __shared__ float2 pr[4][64];
    int t = threadIdx.x;
    if (t < B) gmax[t] = 0u;          // 0 == f2ord(-inf-ish): below any real value
    int d2 = t & 63;
    int h = t >> 6;
    const float2* Wa2 = (const float2*)Wa;
    float2 al = make_float2(0.f, 0.f), ar = make_float2(0.f, 0.f);
    #pragma unroll 8
    for (int k = 0; k < 32; ++k) {
        int e = h * 32 + k;
        float2 w = Wa2[e * 64 + d2];       // Wa[e, 2*d2], Wa[e, 2*d2+1]
        float wl = w_l[e];
        float wr = w_r[e];
        al.x += w.x * wl; al.y += w.y * wl;
        ar.x += w.x * wr; ar.y += w.y * wr;
    }
    pl[h][d2] = al; pr[h][d2] = ar;
    __syncthreads();
    if (t < 64) {
        float2 s = make_float2(0.f, 0.f);
        #pragma unroll
        for (int hh = 0; hh < 4; ++hh) { s.x += pl[hh][t].x; s.y += pl[hh][t].y; }
        ((float2*)u)[t] = s;
    } else if (t < 128) {
        int dd = t - 64;
        float2 s = make_float2(0.f, 0.f);
        #pragma unroll
        for (int hh = 0; hh < 4; ++hh) { s.x += pr[hh][dd].x; s.y += pr[hh][dd].y; }
        ((float2*)(u + D))[dd] = s;
    }
}

// K2: one wave per row. demands (fp32 -> d_out), l (exp2-domain) -> lv,
// r (exp2-domain) -> q4[row].x, and device-scope atomicMax for per-batch rmax.
__global__ __launch_bounds__(256) void k2_rows(
    const float* __restrict__ x,     // [B*N, D]
    const float* __restrict__ Wd,    // [D]
    const float* __restrict__ bd,    // [1]
    const float* __restrict__ u,     // [2*D]
    float* __restrict__ out_dem,     // [B*N] (start of d_out)
    float* __restrict__ lv,          // [B*N]
    float4* __restrict__ q4,         // [B*N] (r, Fp, Fm, -) ; only .x here
    unsigned* __restrict__ gmax) {   // [B]
    int lane = threadIdx.x & 63;
    int row = blockIdx.x * 4 + (threadIdx.x >> 6);
    // lane handles d = 2*lane, 2*lane+1
    float2 xv = ((const float2*)(x + (size_t)row * D))[lane];
    float2 ul2 = ((const float2*)u)[lane];
    float2 ur2 = ((const float2*)(u + D))[lane];
    float2 wv = ((const float2*)Wd)[lane];
    float pl = xv.x * ul2.x + xv.y * ul2.y;
    float pr = xv.x * ur2.x + xv.y * ur2.y;
    float pd = xv.x * wv.x + xv.y * wv.y;
    #pragma unroll
    for (int m = 32; m >= 1; m >>= 1) {
        pl += __shfl_xor(pl, m, 64);
        pr += __shfl_xor(pr, m, 64);
        pd += __shfl_xor(pd, m, 64);
    }
    if (lane == 0) {
        float dem = 1.f / (1.f + __expf(-(pd + bd[0])));
        out_dem[row] = dem;
        lv[row] = pl * LOG2E;            // exp2 domain (lrelu commutes with pos. scale)
        float r = pr * LOG2E;
        q4[row].x = r;
        atomicMax(gmax + (row >> 12), f2ord(r));   // row>>12: 4096 rows per batch
    }
}

// K2b: materialize the column-factor table once per batch:
// q4[j] = (r_j, exp2(r_j - rmax), exp2(0.01*(r_j - rmax)), 0). 32 blocks x 256.
__global__ __launch_bounds__(256) void k2b_fpm(
    float4* __restrict__ q4,
    const unsigned* __restrict__ gmax) {
    int j = blockIdx.x * 256 + threadIdx.x;        // global row 0..B*N-1
    float rmax = ord2f(gmax[j >> 12]);
    float r = q4[j].x;
    float t = r - rmax;
    q4[j] = make_float4(r, exp2f(t), exp2f(0.01f * t), 0.f);
}

// K3: 4 rows per block (same b). No LDS staging, no per-block max phase.
// exp2(lrelu(l+r)-m) == (l+r>0) ? Ep_i*Fp_j : Em_i*Fm_j  with
//   Ep = exp2(l+rmax-m), Em = exp2(0.01*(l+rmax)-m), m = lrelu(l+rmax) (true row max).
// Inner loops are 5-6 short VALU ops per element, zero transcendentals.
__global__ __launch_bounds__(256) void k3_main(
    const float* __restrict__ lv,
    const float4* __restrict__ q4,
    const unsigned* __restrict__ gmax,
    const float* __restrict__ dem_f,      // demands (fp32, start of d_out)
    float* __restrict__ out_g) {          // [B,N,N] fp32
    __shared__ float red[4][8];
    int tid = threadIdx.x;
    int b = blockIdx.x >> 10;             // /1024 blocks-per-b
    int i0 = (blockIdx.x & 1023) << 2;    // *4 rows
    const float4* qb = q4 + (size_t)b * N;
    float rmax = ord2f(gmax[b]);
    int rowbase = b * N + i0;

    float l_[4];
    #pragma unroll
    for (int q = 0; q < 4; ++q) l_[q] = lv[rowbase + q];

    // denominator split-sums: S1 = sum_{l+r>0} Fp_j, S2 = sum_{l+r<=0} Fm_j
    float s1[4] = {0.f, 0.f, 0.f, 0.f}, s2[4] = {0.f, 0.f, 0.f, 0.f};
    #pragma unroll 4
    for (int k = 0; k < N / 256; ++k) {
        float4 v = qb[tid + k * 256];     // (r, Fp, Fm, -) coalesced 16B/lane
        #pragma unroll
        for (int q = 0; q < 4; ++q) {
            bool pos = (l_[q] + v.x) > 0.f;
            s1[q] += pos ? v.y : 0.f;
            s2[q] += pos ? 0.f : v.z;
        }
    }
    #pragma unroll
    for (int m = 32; m >= 1; m >>= 1) {
        #pragma unroll
        for (int q = 0; q < 4; ++q) {
            s1[q] += __shfl_xor(s1[q], m, 64);
            s2[q] += __shfl_xor(s2[q], m, 64);
        }
    }
    int w = tid >> 6;
    if ((tid & 63) == 0) {
        #pragma unroll
        for (int q = 0; q < 4; ++q) { red[w][q] = s1[q]; red[w][4 + q] = s2[q]; }
    }
    __syncthreads();
    float eP[4], eM[4];
    #pragma unroll
    for (int q = 0; q < 4; ++q) {
        float S1 = red[0][q] + red[1][q] + red[2][q] + red[3][q];
        float S2 = red[0][4 + q] + red[1][4 + q] + red[2][4 + q] + red[3][4 + q];
        float t0 = l_[q] + rmax;
        float m0 = lrelu(t0);             // true row max of lrelu(l+r) (monotone)
        float Ep = exp2f(t0 - m0);
        float Em = exp2f(0.01f * t0 - m0);
        float sc = dem_f[rowbase + q] / (Ep * S1 + Em * S2);
        eP[q] = Ep * sc;                  // scale folded into row factors
        eM[q] = Em * sc;
    }

    // Write pass: thread owns columns idx*4..idx*4+3 per row -> 16B/lane stores,
    // perfectly coalesced. Table reads are L1/L2-hot (64 KB/batch shared by 1024 blocks).
    size_t gbase = (size_t)b * N * N + (size_t)i0 * N;
    #pragma unroll
    for (int it = 0; it < 4; ++it) {
        int idx = it * 256 + tid;          // 0..1023, j0 = idx*4
        float4 v0 = qb[idx * 4 + 0];
        float4 v1 = qb[idx * 4 + 1];
        float4 v2 = qb[idx * 4 + 2];
        float4 v3 = qb[idx * 4 + 3];
        #pragma unroll
        for (int q = 0; q < 4; ++q) {
            f32x4 o;
            o.x = (l_[q] + v0.x > 0.f) ? eP[q] * v0.y : eM[q] * v0.z;
            o.y = (l_[q] + v1.x > 0.f) ? eP[q] * v1.y : eM[q] * v1.z;
            o.z = (l_[q] + v2.x > 0.f) ? eP[q] * v2.y : eM[q] * v2.z;
            o.w = (l_[q] + v3.x > 0.f) ? eP[q] * v3.y : eM[q] * v3.z;
            // nontemporal: keep the 134 MB write stream from evicting the hot table
            __builtin_nontemporal_store(o, (f32x4*)(out_g + gbase + (size_t)q * N) + idx);
        }
    }
}

extern "C" void kernel_launch(void* const* d_in, const int* in_sizes, int n_in,
                              void* d_out, int out_size, void* d_ws, size_t ws_size,
                              hipStream_t stream) {
    // inputs: 0 embed_feat(f32 B*N*D), 1 predict_G(int,ignored), 2 W_demand(f32 D),
    //         3 b_demand(f32 1), 4 Wa(f32 D*D), 5 w_l(f32 D), 6 w_r(f32 D)
    const float* x  = (const float*)d_in[0];
    const float* Wd = (const float*)d_in[2];
    const float* bd = (const float*)d_in[3];
    const float* Wa = (const float*)d_in[4];
    const float* wl = (const float*)d_in[5];
    const float* wr = (const float*)d_in[6];

    float* ws = (float*)d_ws;
    float* u  = ws;                                   // 256 floats
    float* lv = ws + 256;                             // 8192 floats
    float4* q4 = (float4*)(ws + 256 + 8192);          // 8192 float4 (offset 33792B, 16B-aligned)
    unsigned* gmax = (unsigned*)(ws + 256 + 8192 + 4 * 8192);  // 2 uints (~165 KB total ws)

    float* out     = (float*)d_out;
    float* out_dem = out;           // [B*N]
    float* out_g   = out + B * N;   // [B,N,N]

    hipLaunchKernelGGL(k1_uvec, dim3(1), dim3(256), 0, stream, Wa, wl, wr, u, gmax);
    hipLaunchKernelGGL(k2_rows, dim3(B * N / 4), dim3(256), 0, stream,
                       x, Wd, bd, u, out_dem, lv, q4, gmax);
    hipLaunchKernelGGL(k2b_fpm, dim3(B * N / 256), dim3(256), 0, stream, q4, gmax);
    hipLaunchKernelGGL(k3_main, dim3(B * N / 4), dim3(256), 0, stream,
                       lv, q4, gmax, out_dem, out_g);
}

// Round 2
// 160.554 us; speedup vs baseline: 1.6154x; 1.6154x over previous
//
#include <hip/hip_runtime.h>
#include <stdint.h>

#define N 4096
#define B 2
#define D 128
#define LOG2E 1.4426950408889634f

typedef float f32x4 __attribute__((ext_vector_type(4)));

__device__ __forceinline__ float lrelu(float t) { return t > 0.f ? t : 0.01f * t; }

// K1: u_l[d] = sum_e Wa[e*D+d]*w_l[e]; u_r likewise. 1 block x 256 threads.
__global__ __launch_bounds__(256) void k1_uvec(
    const float* __restrict__ Wa,
    const float* __restrict__ w_l,
    const float* __restrict__ w_r,
    float* __restrict__ u) {          // u[0..D)=u_l, u[D..2D)=u_r
    __shared__ float2 pl[4][64];
    __shared__ float2 pr[4][64];
    int t = threadIdx.x;
    int d2 = t & 63;
    int h = t >> 6;
    const float2* Wa2 = (const float2*)Wa;
    float2 al = make_float2(0.f, 0.f), ar = make_float2(0.f, 0.f);
    #pragma unroll 8
    for (int k = 0; k < 32; ++k) {
        int e = h * 32 + k;
        float2 w = Wa2[e * 64 + d2];       // Wa[e, 2*d2], Wa[e, 2*d2+1]
        float wl = w_l[e];
        float wr = w_r[e];
        al.x += w.x * wl; al.y += w.y * wl;
        ar.x += w.x * wr; ar.y += w.y * wr;
    }
    pl[h][d2] = al; pr[h][d2] = ar;
    __syncthreads();
    if (t < 64) {
        float2 s = make_float2(0.f, 0.f);
        #pragma unroll
        for (int hh = 0; hh < 4; ++hh) { s.x += pl[hh][t].x; s.y += pl[hh][t].y; }
        ((float2*)u)[t] = s;
    } else if (t < 128) {
        int dd = t - 64;
        float2 s = make_float2(0.f, 0.f);
        #pragma unroll
        for (int hh = 0; hh < 4; ++hh) { s.x += pr[hh][dd].x; s.y += pr[hh][dd].y; }
        ((float2*)(u + D))[dd] = s;
    }
}

// K2: one wave per row. demands (fp32 -> d_out), l (exp2-domain) -> lv,
// r (exp2-domain) -> q4[row].x. NO atomics (the r1 atomicMax serialized 8192
// same-address device-scope RMWs -> 97 us; k2b now owns the max-reduce).
__global__ __launch_bounds__(256) void k2_rows(
    const float* __restrict__ x,     // [B*N, D]
    const float* __restrict__ Wd,    // [D]
    const float* __restrict__ bd,    // [1]
    const float* __restrict__ u,     // [2*D]
    float* __restrict__ out_dem,     // [B*N] (start of d_out)
    float* __restrict__ lv,          // [B*N]
    float4* __restrict__ q4) {       // [B*N] (r, Fp, Fm, -) ; only .x here
    int lane = threadIdx.x & 63;
    int row = blockIdx.x * 4 + (threadIdx.x >> 6);
    // lane handles d = 2*lane, 2*lane+1
    float2 xv = ((const float2*)(x + (size_t)row * D))[lane];
    float2 ul2 = ((const float2*)u)[lane];
    float2 ur2 = ((const float2*)(u + D))[lane];
    float2 wv = ((const float2*)Wd)[lane];
    float pl = xv.x * ul2.x + xv.y * ul2.y;
    float pr = xv.x * ur2.x + xv.y * ur2.y;
    float pd = xv.x * wv.x + xv.y * wv.y;
    #pragma unroll
    for (int m = 32; m >= 1; m >>= 1) {
        pl += __shfl_xor(pl, m, 64);
        pr += __shfl_xor(pr, m, 64);
        pd += __shfl_xor(pd, m, 64);
    }
    if (lane == 0) {
        float dem = 1.f / (1.f + __expf(-(pd + bd[0])));
        out_dem[row] = dem;
        lv[row] = pl * LOG2E;            // exp2 domain (lrelu commutes with pos. scale)
        q4[row].x = pr * LOG2E;
    }
}

// K2b: one block per batch. Block-reduce rmax over the 4096 r values (shfl+LDS,
// zero atomics), then materialize q4[j] = (r, exp2(r-rmax), exp2(0.01*(r-rmax)), 0).
__global__ __launch_bounds__(1024) void k2b_fpm(
    float4* __restrict__ q4,
    float* __restrict__ gmax) {        // [B] rmax as plain float
    __shared__ float red[16];
    int b = blockIdx.x;
    int tid = threadIdx.x;
    float4* qb = q4 + (size_t)b * N;
    float r[4];
    float m = -3.402823466e38f;
    #pragma unroll
    for (int k = 0; k < 4; ++k) {
        r[k] = qb[tid + k * 1024].x;
        m = fmaxf(m, r[k]);
    }
    #pragma unroll
    for (int s = 32; s >= 1; s >>= 1) m = fmaxf(m, __shfl_xor(m, s, 64));
    if ((tid & 63) == 0) red[tid >> 6] = m;
    __syncthreads();
    float rmax = red[0];
    #pragma unroll
    for (int w = 1; w < 16; ++w) rmax = fmaxf(rmax, red[w]);
    if (tid == 0) gmax[b] = rmax;
    #pragma unroll
    for (int k = 0; k < 4; ++k) {
        float t = r[k] - rmax;
        qb[tid + k * 1024] = make_float4(r[k], exp2f(t), exp2f(0.01f * t), 0.f);
    }
}

// K3: 4 rows per block (same b). No LDS staging, no per-block max phase.
// exp2(lrelu(l+r)-m) == (l+r>0) ? Ep_i*Fp_j : Em_i*Fm_j  with
//   Ep = exp2(l+rmax-m), Em = exp2(0.01*(l+rmax)-m), m = lrelu(l+rmax) (true row max).
// Inner loops are 5-6 short VALU ops per element, zero transcendentals.
__global__ __launch_bounds__(256) void k3_main(
    const float* __restrict__ lv,
    const float4* __restrict__ q4,
    const float* __restrict__ gmax,
    const float* __restrict__ dem_f,      // demands (fp32, start of d_out)
    float* __restrict__ out_g) {          // [B,N,N] fp32
    __shared__ float red[4][8];
    int tid = threadIdx.x;
    int b = blockIdx.x >> 10;             // /1024 blocks-per-b
    int i0 = (blockIdx.x & 1023) << 2;    // *4 rows
    const float4* qb = q4 + (size_t)b * N;
    float rmax = gmax[b];
    int rowbase = b * N + i0;

    float l_[4];
    #pragma unroll
    for (int q = 0; q < 4; ++q) l_[q] = lv[rowbase + q];

    // denominator split-sums: S1 = sum_{l+r>0} Fp_j, S2 = sum_{l+r<=0} Fm_j
    float s1[4] = {0.f, 0.f, 0.f, 0.f}, s2[4] = {0.f, 0.f, 0.f, 0.f};
    #pragma unroll 4
    for (int k = 0; k < N / 256; ++k) {
        float4 v = qb[tid + k * 256];     // (r, Fp, Fm, -) coalesced 16B/lane
        #pragma unroll
        for (int q = 0; q < 4; ++q) {
            bool pos = (l_[q] + v.x) > 0.f;
            s1[q] += pos ? v.y : 0.f;
            s2[q] += pos ? 0.f : v.z;
        }
    }
    #pragma unroll
    for (int m = 32; m >= 1; m >>= 1) {
        #pragma unroll
        for (int q = 0; q < 4; ++q) {
            s1[q] += __shfl_xor(s1[q], m, 64);
            s2[q] += __shfl_xor(s2[q], m, 64);
        }
    }
    int w = tid >> 6;
    if ((tid & 63) == 0) {
        #pragma unroll
        for (int q = 0; q < 4; ++q) { red[w][q] = s1[q]; red[w][4 + q] = s2[q]; }
    }
    __syncthreads();
    float eP[4], eM[4];
    #pragma unroll
    for (int q = 0; q < 4; ++q) {
        float S1 = red[0][q] + red[1][q] + red[2][q] + red[3][q];
        float S2 = red[0][4 + q] + red[1][4 + q] + red[2][4 + q] + red[3][4 + q];
        float t0 = l_[q] + rmax;
        float m0 = lrelu(t0);             // true row max of lrelu(l+r) (monotone)
        float Ep = exp2f(t0 - m0);
        float Em = exp2f(0.01f * t0 - m0);
        float sc = dem_f[rowbase + q] / (Ep * S1 + Em * S2);
        eP[q] = Ep * sc;                  // scale folded into row factors
        eM[q] = Em * sc;
    }

    // Write pass: thread owns columns idx*4..idx*4+3 per row -> 16B/lane stores,
    // perfectly coalesced. Plain stores (r0 measured faster than NT here).
    size_t gbase = (size_t)b * N * N + (size_t)i0 * N;
    #pragma unroll
    for (int it = 0; it < 4; ++it) {
        int idx = it * 256 + tid;          // 0..1023, j0 = idx*4
        float4 v0 = qb[idx * 4 + 0];
        float4 v1 = qb[idx * 4 + 1];
        float4 v2 = qb[idx * 4 + 2];
        float4 v3 = qb[idx * 4 + 3];
        #pragma unroll
        for (int q = 0; q < 4; ++q) {
            f32x4 o;
            o.x = (l_[q] + v0.x > 0.f) ? eP[q] * v0.y : eM[q] * v0.z;
            o.y = (l_[q] + v1.x > 0.f) ? eP[q] * v1.y : eM[q] * v1.z;
            o.z = (l_[q] + v2.x > 0.f) ? eP[q] * v2.y : eM[q] * v2.z;
            o.w = (l_[q] + v3.x > 0.f) ? eP[q] * v3.y : eM[q] * v3.z;
            *((f32x4*)(out_g + gbase + (size_t)q * N) + idx) = o;
        }
    }
}

extern "C" void kernel_launch(void* const* d_in, const int* in_sizes, int n_in,
                              void* d_out, int out_size, void* d_ws, size_t ws_size,
                              hipStream_t stream) {
    // inputs: 0 embed_feat(f32 B*N*D), 1 predict_G(int,ignored), 2 W_demand(f32 D),
    //         3 b_demand(f32 1), 4 Wa(f32 D*D), 5 w_l(f32 D), 6 w_r(f32 D)
    const float* x  = (const float*)d_in[0];
    const float* Wd = (const float*)d_in[2];
    const float* bd = (const float*)d_in[3];
    const float* Wa = (const float*)d_in[4];
    const float* wl = (const float*)d_in[5];
    const float* wr = (const float*)d_in[6];

    float* ws = (float*)d_ws;
    float* u  = ws;                                   // 256 floats
    float* lv = ws + 256;                             // 8192 floats
    float4* q4 = (float4*)(ws + 256 + 8192);          // 8192 float4 (16B-aligned)
    float* gmax = ws + 256 + 8192 + 4 * 8192;         // 2 floats

    float* out     = (float*)d_out;
    float* out_dem = out;           // [B*N]
    float* out_g   = out + B * N;   // [B,N,N]

    hipLaunchKernelGGL(k1_uvec, dim3(1), dim3(256), 0, stream, Wa, wl, wr, u);
    hipLaunchKernelGGL(k2_rows, dim3(B * N / 4), dim3(256), 0, stream,
                       x, Wd, bd, u, out_dem, lv, q4);
    hipLaunchKernelGGL(k2b_fpm, dim3(B), dim3(1024), 0, stream, q4, gmax);
    hipLaunchKernelGGL(k3_main, dim3(B * N / 4), dim3(256), 0, stream,
                       lv, q4, gmax, out_dem, out_g);
}